// Round 6
// baseline (11346.912 us; speedup 1.0000x reference)
//
#include <hip/hip_runtime.h>

#define T_SEQ   1024
#define T_STEPS 1023
#define BATCH   128
#define DIM     256
#define HID     1024
#define VOUT    128
#define WGS     256
#define HSLOT   131072   // ushorts per t-slot: 8 group-slices x 16384
#define SLICE_E 16384    // h elems per group-slice per t, frag-blocked [hk 32][lq 4][row 16][j 8]

typedef __attribute__((ext_vector_type(8))) short short8;
typedef __attribute__((ext_vector_type(4))) float floatx4;

__device__ __forceinline__ unsigned short f2bf(float x) {
    union { float f; unsigned u; } v; v.f = x;
    unsigned r = v.u + 0x7FFFu + ((v.u >> 16) & 1u);   // RNE
    return (unsigned short)(r >> 16);
}
__device__ __forceinline__ float sigm(float x) { return 1.0f / (1.0f + __expf(-x)); }

// ---------------- prep kernels ----------------

// Unified gate weights (x-part and h-part), bf16, wave-fragment order:
// [cg 64][w 8][ct 2][kki 10][lane 64][j 8].  w = cw*4+kw (cw=w>>2, kw=w&3).
// Frag element: local gate col lgc = cw*32 + ct*16 + (lane&15); gate = lgc>>4,
// p = lgc&15; W row R = gate*HID + cg*16 + p; K elem k = kw*320 + kki*32 +
// (lane>>4)*8 + j; k<256 -> Wih[R][k], else Whh[R][k-256].
__global__ void pack_w(const float* __restrict__ Wih, const float* __restrict__ Whh,
                       unsigned short* __restrict__ Wp) {
    const size_t idx = (size_t)blockIdx.x * 256 + threadIdx.x;
    if (idx >= (size_t)64 * 8 * 2 * 10 * 64 * 8) return;   // 5,242,880
    const int j   = (int)(idx & 7);
    const int l   = (int)((idx >> 3) & 63);
    const int rest = (int)(idx >> 9);
    const int kki  = rest % 10;
    const int rest2 = rest / 10;
    const int ct  = rest2 & 1;
    const int w   = (rest2 >> 1) & 7;
    const int cg  = rest2 >> 4;
    const int cw = w >> 2, kw = w & 3;
    const int lgc = cw * 32 + ct * 16 + (l & 15);
    const int gate = lgc >> 4, p = lgc & 15;
    const int R = gate * HID + cg * 16 + p;
    const int k = kw * 320 + kki * 32 + (l >> 4) * 8 + j;
    const float v = (k < 256) ? Wih[(size_t)R * DIM + k] : Whh[(size_t)R * HID + (k - 256)];
    Wp[idx] = f2bf(v);
}

// bias in natural (gate*H + hcol) order
__global__ void pack_bias(const float* __restrict__ bih, const float* __restrict__ bhh,
                          float* __restrict__ bc) {
    const int idx = blockIdx.x * 256 + threadIdx.x;
    if (idx < 4096) bc[idx] = bih[idx] + bhh[idx];
}

__global__ void pack_wout(const float* __restrict__ Wo, unsigned short* __restrict__ WoBf) {
    const int idx = blockIdx.x * 256 + threadIdx.x;
    if (idx < VOUT * HID) WoBf[idx] = f2bf(Wo[idx]);
}

// sequence [B, T, D] fp32 -> Xb [t][ga 2][sp 4][xk 8][lq 4][row 16][j 8] bf16
__global__ void pack_x(const float* __restrict__ seq, unsigned short* __restrict__ Xb) {
    const size_t idx = (size_t)blockIdx.x * 256 + threadIdx.x;
    if (idx >= (size_t)T_STEPS * BATCH * DIM) return;
    const int j   = (int)(idx & 7);
    const int row = (int)((idx >> 3) & 15);
    const int lq  = (int)((idx >> 7) & 3);
    const int xk  = (int)((idx >> 9) & 7);
    const int sp  = (int)((idx >> 12) & 3);
    const int ga  = (int)((idx >> 14) & 1);
    const int t   = (int)(idx >> 15);
    const int b = ga * 64 + sp * 16 + row;
    const int k = xk * 32 + lq * 8 + j;
    Xb[idx] = f2bf(seq[((size_t)b * T_SEQ + t) * DIM + k]);
}

__global__ void init_state(unsigned short* __restrict__ Hb, int* __restrict__ bar) {
    const int idx = blockIdx.x * 256 + threadIdx.x;
    if (idx < HSLOT) Hb[idx] = 0;          // t=0 slot zeros
    if (idx < 4096) bar[idx] = 0;          // flags (epoch 0 = h(0) ready)
}

// ---------------- persistent recurrent kernel ----------------
// 256 WGs x 512 threads, 1 WG/CU (LDS > 80 KB forces it). PING-PONG: WG
// (sp=wg&3, cg=wg>>2) runs TWO independent 16-row recurrences (group A rows
// 0..63, group B rows 64..127) with the SAME weights (16 h-cols, 64 gate cols,
// full K in 4 kw-quarters x 2 cw-halves). While one group's h(t+1) exchange
// (store->IC->flag->load) is in flight, the other group's step computes -> the
// exchange latency is hidden. Per-group per-WG store: one contiguous 512 B
// agent-scope block by wave 7 (+drain+flag, no extra barrier). Consumers poll
// <=20 producer flags lane-parallel, then prefetch A-frags to registers.
__global__ __launch_bounds__(512, 1) void lstm_persist(
    const unsigned short* __restrict__ Xb,
    unsigned short* __restrict__ Hblk,
    const unsigned short* __restrict__ Wp,
    const float* __restrict__ bc,
    int* __restrict__ bar)
{
    __shared__ float gl[2][4][16][68];        // 34.8 KB gate partials (per group)
    __shared__ unsigned short hstage[2][256]; // 1 KB    h repack stage
    __shared__ char icepad[61440];            // LDS pad -> 1 WG/CU

    const int wg  = blockIdx.x;
    const int sp  = wg & 3;
    const int cg  = wg >> 2;          // 0..63 -> h-cols [cg*16, cg*16+16)
    const int tid = threadIdx.x;
    const int w   = tid >> 6;
    const int l   = tid & 63;
    const int lr  = l & 15;
    const int lq  = l >> 4;
    const int kw  = w & 3;
    const int cw  = w >> 2;
    const int cwb = cw * 32;
    const int lq4 = lq * 4;
    const int gsA = sp;               // group-slice ids
    const int gsB = 4 + sp;

    if (tid == 511 && bar[4000] != 0) icepad[bar[4001] & 32767] = 1;  // keep pad

    // ---- B-weight frags -> unified RF: 20 x short8 (covers x+h for this wave)
    const short8* wpw = (const short8*)Wp + (size_t)((cg * 8 + w) * 20) * 64 + l;
    short8 bw[20];
    #pragma unroll
    for (int i = 0; i < 20; ++i) bw[i] = wpw[i * 64];

    // ---- epilogue constants: thread (tid<256) -> cell (row er, local col ep)
    const int er = (tid >> 4) & 15;
    const int ep = tid & 15;
    const int hsi = ((ep >> 3) * 16 + er) * 8 + (ep & 7);
    const float bi  = bc[0 * HID + cg * 16 + ep];
    const float bf_ = bc[1 * HID + cg * 16 + ep];
    const float bg  = bc[2 * HID + cg * 16 + ep];
    const float bo_ = bc[3 * HID + cg * 16 + ep];
    float cregA = 0.f, cregB = 0.f;

    // ---- poll set: producers of this wave's h-frags ----
    const int cnt  = (kw == 0) ? 4 : 20;
    const int base = (kw == 0) ? 0 : (kw * 20 - 16);
    const int pcg  = base + (l % cnt);
    const unsigned short* xbA = Xb + (size_t)gsA * 4096;
    const unsigned short* xbB = Xb + (size_t)gsB * 4096;

    const floatx4 zf4 = {0.f, 0.f, 0.f, 0.f};
    short8 avA[10], avB[10];

#define POLL_PREF(AV, GS, XBASE, NN) { \
    const int* fp_ = bar + (GS) * 64 + pcg; \
    int budl_ = 1 << 20; \
    while (true) { \
        const int f_ = __hip_atomic_load(fp_, __ATOMIC_RELAXED, __HIP_MEMORY_SCOPE_AGENT); \
        if (__all(f_ >= (NN))) break; \
        if (--budl_ < 0) break; \
    } \
    __builtin_amdgcn_sched_barrier(0); \
    if (kw == 0) { \
        const unsigned short* xp_ = (XBASE) + (size_t)(NN) * 32768 + (size_t)l * 8; \
        _Pragma("unroll") \
        for (int i_ = 0; i_ < 8; ++i_) AV[i_] = *(const short8*)(xp_ + i_ * 512); \
        const unsigned short* hp_ = Hblk + (size_t)(NN) * HSLOT + (size_t)(GS) * SLICE_E + (size_t)l * 8; \
        AV[8] = *(const short8*)(hp_); \
        AV[9] = *(const short8*)(hp_ + 512); \
    } else { \
        const unsigned short* hp_ = Hblk + (size_t)(NN) * HSLOT + (size_t)(GS) * SLICE_E \
            + (size_t)(kw * 10 - 8) * 512 + (size_t)l * 8; \
        _Pragma("unroll") \
        for (int i_ = 0; i_ < 10; ++i_) AV[i_] = *(const short8*)(hp_ + i_ * 512); \
    } }

#define COMPUTE_GL(G, AV) { \
    floatx4 a0_ = zf4, a1_ = zf4; \
    _Pragma("unroll") \
    for (int i_ = 0; i_ < 10; ++i_) { \
        a0_ = __builtin_amdgcn_mfma_f32_16x16x32_bf16(AV[i_], bw[i_],      a0_, 0, 0, 0); \
        a1_ = __builtin_amdgcn_mfma_f32_16x16x32_bf16(AV[i_], bw[10 + i_], a1_, 0, 0, 0); \
    } \
    _Pragma("unroll") \
    for (int rr_ = 0; rr_ < 4; ++rr_) { \
        gl[G][kw][lq4 + rr_][cwb + lr]      = a0_[rr_]; \
        gl[G][kw][lq4 + rr_][cwb + 16 + lr] = a1_[rr_]; \
    } }

#define EPI_STAGE(G, CREG) { \
    __syncthreads(); \
    if (tid < 256) { \
        float gi_ = bi, gf_ = bf_, gg_ = bg, go_ = bo_; \
        _Pragma("unroll") \
        for (int q_ = 0; q_ < 4; ++q_) { \
            gi_ += gl[G][q_][er][ 0 + ep]; \
            gf_ += gl[G][q_][er][16 + ep]; \
            gg_ += gl[G][q_][er][32 + ep]; \
            go_ += gl[G][q_][er][48 + ep]; \
        } \
        const float iv_ = sigm(gi_), fv_ = sigm(gf_), ov_ = sigm(go_); \
        const float gv_ = tanhf(gg_); \
        CREG = fv_ * CREG + iv_ * gv_; \
        hstage[G][hsi] = f2bf(ov_ * tanhf(CREG)); \
    } \
    __syncthreads(); }

#define W7_STORE_FLAG(G, GS, TS) { \
    if (w == 7) { \
        const unsigned* hu_ = (const unsigned*)&hstage[G][l * 4]; \
        const unsigned u0_ = hu_[0], u1_ = hu_[1]; \
        const unsigned long long vv_ = u0_ | ((unsigned long long)u1_ << 32); \
        unsigned long long* hp_ = (unsigned long long*)(Hblk \
            + (size_t)(TS) * HSLOT + (size_t)(GS) * SLICE_E \
            + (size_t)(cg >> 1) * 512 + (size_t)(cg & 1) * 256) + l; \
        __hip_atomic_store(hp_, vv_, __ATOMIC_RELAXED, __HIP_MEMORY_SCOPE_AGENT); \
        asm volatile("s_waitcnt vmcnt(0)" ::: "memory"); \
        if (l == 0) \
            __hip_atomic_store(bar + (GS) * 64 + cg, (TS), \
                               __ATOMIC_RELAXED, __HIP_MEMORY_SCOPE_AGENT); \
    } }

    // prologue: prefetch A(0) (flags init 0 -> slot 0 ready)
    POLL_PREF(avA, gsA, xbA, 0);

    for (int t = 0; t < T_STEPS; ++t) {
        // B(t) data: flags set during previous iteration's B phase -> ~instant;
        // prefetch loads overlap the whole A phase.
        POLL_PREF(avB, gsB, xbB, t);

        // ---- group A, step t ----
        COMPUTE_GL(0, avA);
        EPI_STAGE(0, cregA);
        W7_STORE_FLAG(0, gsA, t + 1);

        // ---- group B, step t ----
        COMPUTE_GL(1, avB);
        EPI_STAGE(1, cregB);
        // A(t+1): flags were set one B-phase ago; spin is short and the
        // prefetch flies under wave7's B store/drain + next loop-top poll.
        if (t + 1 < T_STEPS) POLL_PREF(avA, gsA, xbA, t + 1);
        W7_STORE_FLAG(1, gsB, t + 1);
    }
#undef POLL_PREF
#undef COMPUTE_GL
#undef EPI_STAGE
#undef W7_STORE_FLAG
}

// ---------------- deferred head: logits + log-softmax ----------------
__global__ __launch_bounds__(256, 2) void head_ls(
    const unsigned short* __restrict__ Hblk,
    const unsigned short* __restrict__ Wo,
    const float* __restrict__ bo,
    float* __restrict__ out)
{
    const int bg = blockIdx.x;    // 0..7 == group-slice gs (rows bg*16..+16)
    const int t  = blockIdx.y;    // 0..1022
    const int tid = threadIdx.x;
    const int w  = tid >> 6;
    const int l  = tid & 63;
    const int lr = l & 15;
    const int lq = l >> 4;
    const int b0 = bg * 16;

    const short8* ap = (const short8*)(Hblk + (size_t)(t + 1) * HSLOT
                       + (size_t)bg * SLICE_E) + l;
    const unsigned short* bp0 = Wo + (size_t)(w * 32 + lr) * HID + lq * 8;
    const unsigned short* bp1 = Wo + (size_t)(w * 32 + 16 + lr) * HID + lq * 8;

    floatx4 a0 = {0.f, 0.f, 0.f, 0.f}, a1 = {0.f, 0.f, 0.f, 0.f};
    #pragma unroll 8
    for (int kk = 0; kk < 32; ++kk) {
        short8 a   = ap[kk * 64];
        short8 b0v = *(const short8*)(bp0 + kk * 32);
        short8 b1v = *(const short8*)(bp1 + kk * 32);
        a0 = __builtin_amdgcn_mfma_f32_16x16x32_bf16(a, b0v, a0, 0, 0, 0);
        a1 = __builtin_amdgcn_mfma_f32_16x16x32_bf16(a, b1v, a1, 0, 0, 0);
    }

    __shared__ float lg[16][132];
    #pragma unroll
    for (int r = 0; r < 4; ++r) {
        lg[lq * 4 + r][w * 32 + lr]      = a0[r] + bo[w * 32 + lr];
        lg[lq * 4 + r][w * 32 + 16 + lr] = a1[r] + bo[w * 32 + 16 + lr];
    }
    __syncthreads();

    const int row = tid >> 4;
    const int c   = tid & 15;
    float vals[8];
    float m = -1e30f;
    #pragma unroll
    for (int jv = 0; jv < 8; ++jv) { vals[jv] = lg[row][c + jv * 16]; m = fmaxf(m, vals[jv]); }
    #pragma unroll
    for (int d = 8; d >= 1; d >>= 1) m = fmaxf(m, __shfl_xor(m, d, 16));
    float ssum = 0.f;
    #pragma unroll
    for (int jv = 0; jv < 8; ++jv) ssum += __expf(vals[jv] - m);
    #pragma unroll
    for (int d = 8; d >= 1; d >>= 1) ssum += __shfl_xor(ssum, d, 16);
    const float lse = m + __logf(ssum);

    float* op = out + ((size_t)(b0 + row) * T_STEPS + t) * VOUT;
    #pragma unroll
    for (int jv = 0; jv < 8; ++jv) op[c + jv * 16] = vals[jv] - lse;
}

// ---------------- launcher ----------------
extern "C" void kernel_launch(void* const* d_in, const int* in_sizes, int n_in,
                              void* d_out, int out_size, void* d_ws, size_t ws_size,
                              hipStream_t stream) {
    const float* seq  = (const float*)d_in[0];
    const float* Wih  = (const float*)d_in[1];
    const float* Whh  = (const float*)d_in[2];
    const float* bih  = (const float*)d_in[3];
    const float* bhh  = (const float*)d_in[4];
    const float* Wout = (const float*)d_in[5];
    const float* bout = (const float*)d_in[6];
    float* out = (float*)d_out;

    char* p = (char*)d_ws;
    unsigned short* Wp   = (unsigned short*)p; p += (size_t)64 * 8 * 2 * 10 * 64 * 8 * 2;   // 10.5 MB
    unsigned short* WoBf = (unsigned short*)p; p += (size_t)VOUT * HID * 2;                 // 256 KB
    float*          bc   = (float*)p;          p += (size_t)4096 * 4;                       // 16 KB
    int*            bar  = (int*)p;            p += (size_t)4096 * 4;                       // 16 KB
    unsigned short* Xb   = (unsigned short*)p; p += (size_t)T_STEPS * BATCH * DIM * 2;      // 67 MB
    unsigned short* Hblk = (unsigned short*)p; p += (size_t)(T_STEPS + 1) * HSLOT * 2;      // 268 MB

    pack_w    <<<20480, 256, 0, stream>>>(Wih, Whh, Wp);
    pack_bias <<<16,    256, 0, stream>>>(bih, bhh, bc);
    pack_wout <<<512,   256, 0, stream>>>(Wout, WoBf);
    pack_x    <<<130944,256, 0, stream>>>(seq, Xb);
    init_state<<<512,   256, 0, stream>>>(Hblk, bar);

    lstm_persist<<<WGS, 512, 0, stream>>>(Xb, Hblk, Wp, bc, bar);

    head_ls<<<dim3(8, T_STEPS), 256, 0, stream>>>(Hblk, WoBf, bout, out);
}